// Round 1
// baseline (268.205 us; speedup 1.0000x reference)
//
#include <hip/hip_runtime.h>
#include <hip/hip_bf16.h>
#include <stdint.h>

// Problem: B=2, N=2048, DIM=1024, HEADS=8, DIM_HEAD=64, INNER=512
// Pipeline: LN(dim=1 stats) -> qkv GEMM -> flash attention -> out GEMM
// All GEMM/attention math in bf16 MFMA (16x16x32), fp32 accumulate.

#define B_ 2
#define N_ 2048
#define DIM_ 1024
#define HEADS_ 8
#define DH_ 64
#define INNER_ 512
#define ROWS_ (B_ * N_)       // 4096
#define QKVN_ (3 * INNER_)    // 1536

typedef __bf16 bf16x8 __attribute__((ext_vector_type(8)));
typedef float floatx4 __attribute__((ext_vector_type(4)));

__device__ __forceinline__ ushort f2bf(float f) {
    union { float f; uint32_t u; } v; v.f = f;
    uint32_t u = v.u;
    u += 0x7fffu + ((u >> 16) & 1u);   // round-to-nearest-even
    return (ushort)(u >> 16);
}

// ---------------------------------------------------------------------------
// K1: partial column stats. Stats are over the SEQUENCE axis n for each (b,c).
// grid (8, 32), block 256.  chunk ch covers 64 n-values.
__global__ __launch_bounds__(256) void stats_partial(
    const float* __restrict__ x, float* __restrict__ ps, float* __restrict__ pq) {
    int gd = blockIdx.x * 256 + threadIdx.x;   // 0..2047 = b*1024 + c
    int ch = blockIdx.y;                        // 0..31
    int b = gd >> 10, c = gd & 1023;
    const float* p = x + (size_t)(b * N_ + ch * 64) * DIM_ + c;
    float s = 0.f, q = 0.f;
#pragma unroll 4
    for (int n = 0; n < 64; ++n) { float v = p[(size_t)n * DIM_]; s += v; q += v * v; }
    ps[ch * 2048 + gd] = s;
    pq[ch * 2048 + gd] = q;
}

// K2: finalize mean/rstd. grid 8, block 256.
__global__ __launch_bounds__(256) void stats_final(
    const float* __restrict__ ps, const float* __restrict__ pq,
    float* __restrict__ meanb, float* __restrict__ rstdb) {
    int gd = blockIdx.x * 256 + threadIdx.x;
    float s = 0.f, q = 0.f;
#pragma unroll
    for (int ch = 0; ch < 32; ++ch) { s += ps[ch * 2048 + gd]; q += pq[ch * 2048 + gd]; }
    float mean = s * (1.f / N_);
    float var = q * (1.f / N_) - mean * mean;
    meanb[gd] = mean;
    rstdb[gd] = rsqrtf(var + 1e-5f);
}

// K3: xn = (x - mean) * rstd * g, cast bf16. grid 4096, block 256, 4 elem/thread.
__global__ __launch_bounds__(256) void norm_cast(
    const float* __restrict__ x, const float* __restrict__ g,
    const float* __restrict__ meanb, const float* __restrict__ rstdb,
    ushort* __restrict__ xn) {
    size_t e = ((size_t)blockIdx.x * 256 + threadIdx.x) * 4;
    int row = (int)(e >> 10);
    int c = (int)(e & 1023);
    int b = row >> 11;
    float4 xv = *(const float4*)&x[e];
    float4 gv = *(const float4*)&g[c];
    float4 mv = *(const float4*)&meanb[b * DIM_ + c];
    float4 rv = *(const float4*)&rstdb[b * DIM_ + c];
    ushort4 o;
    o.x = f2bf((xv.x - mv.x) * rv.x * gv.x);
    o.y = f2bf((xv.y - mv.y) * rv.y * gv.y);
    o.z = f2bf((xv.z - mv.z) * rv.z * gv.z);
    o.w = f2bf((xv.w - mv.w) * rv.w * gv.w);
    *(ushort4*)&xn[e] = o;
}

// K4: transpose + cast weights: src[R][C] fp32 -> dst[C][R] bf16, * scale.
// grid (R/32, C/32), block 256.
__global__ __launch_bounds__(256) void transpose_cast(
    const float* __restrict__ src, ushort* __restrict__ dst,
    int R, int C, float scale) {
    __shared__ float tile[32][33];
    int r0 = blockIdx.x * 32, c0 = blockIdx.y * 32;
    int i = threadIdx.x >> 5;   // 0..7
    int j = threadIdx.x & 31;
#pragma unroll
    for (int p = 0; p < 4; ++p)
        tile[i + 8 * p][j] = src[(size_t)(r0 + i + 8 * p) * C + c0 + j] * scale;
    __syncthreads();
#pragma unroll
    for (int p = 0; p < 4; ++p)
        dst[(size_t)(c0 + i + 8 * p) * R + r0 + j] = f2bf(tile[j][i + 8 * p]);
}

// ---------------------------------------------------------------------------
// K5: bf16 GEMM  C[M,N] = A[M,K] @ Bt[N,K]^T.  128x128 tile, 4 waves (2x2),
// 64x64 per wave as 4x4 MFMA 16x16x32 tiles, BK=64, global_load_lds staging.
template <bool OUT_BF16>
__global__ __launch_bounds__(256) void gemm_bt(
    const ushort* __restrict__ A, const ushort* __restrict__ Bt,
    void* __restrict__ C, int M, int N, int K) {
    __shared__ __align__(16) ushort sA[128 * 64];
    __shared__ __align__(16) ushort sB[128 * 64];
    const int tx = threadIdx.x;
    const int w = tx >> 6;
    const int l = tx & 63;
    const int tileM = blockIdx.x * 128;
    const int tileN = blockIdx.y * 128;
    const int wm = w & 1, wn = w >> 1;
    const int lr = l & 15, lq = l >> 4;
    const int srow = l >> 3;            // 0..7 within staging chunk
    const int scol = (l & 7) * 8;       // bf16 elements

    floatx4 acc[4][4] = {};

    for (int k0 = 0; k0 < K; k0 += 64) {
#pragma unroll
        for (int c = 0; c < 4; ++c) {
            int rowA = tileM + 32 * w + 8 * c + srow;
            int rowB = tileN + 32 * w + 8 * c + srow;
            const ushort* gA = A + (size_t)rowA * K + k0 + scol;
            const ushort* gB = Bt + (size_t)rowB * K + k0 + scol;
            __builtin_amdgcn_global_load_lds(
                (const __attribute__((address_space(1))) void*)gA,
                (__attribute__((address_space(3))) void*)&sA[(32 * w + 8 * c) * 64], 16, 0, 0);
            __builtin_amdgcn_global_load_lds(
                (const __attribute__((address_space(1))) void*)gB,
                (__attribute__((address_space(3))) void*)&sB[(32 * w + 8 * c) * 64], 16, 0, 0);
        }
        __syncthreads();
#pragma unroll
        for (int s = 0; s < 2; ++s) {
            bf16x8 a[4], b[4];
#pragma unroll
            for (int mi = 0; mi < 4; ++mi)
                a[mi] = *(const bf16x8*)&sA[(64 * wm + 16 * mi + lr) * 64 + s * 32 + 8 * lq];
#pragma unroll
            for (int ni = 0; ni < 4; ++ni)
                b[ni] = *(const bf16x8*)&sB[(64 * wn + 16 * ni + lr) * 64 + s * 32 + 8 * lq];
#pragma unroll
            for (int mi = 0; mi < 4; ++mi)
#pragma unroll
                for (int ni = 0; ni < 4; ++ni)
                    acc[mi][ni] = __builtin_amdgcn_mfma_f32_16x16x32_bf16(
                        a[mi], b[ni], acc[mi][ni], 0, 0, 0);
        }
        __syncthreads();
    }

#pragma unroll
    for (int mi = 0; mi < 4; ++mi)
#pragma unroll
        for (int ni = 0; ni < 4; ++ni)
#pragma unroll
            for (int reg = 0; reg < 4; ++reg) {
                int row = tileM + 64 * wm + 16 * mi + 4 * lq + reg;
                int col = tileN + 64 * wn + 16 * ni + lr;
                float v = acc[mi][ni][reg];
                if (OUT_BF16)
                    ((ushort*)C)[(size_t)row * N + col] = f2bf(v);
                else
                    ((float*)C)[(size_t)row * N + col] = v;
            }
}

// ---------------------------------------------------------------------------
// K6: flash attention. grid (32 qtiles, 16 b*h), block 256 (4 waves x 16 rows).
// qkv: [4096][1536] bf16 (q | k | v, head h at cols h*64).  q pre-scaled 1/8.
// attn out: [4096][512] bf16.
__global__ __launch_bounds__(256) void flash_attn(
    const ushort* __restrict__ qkv, ushort* __restrict__ attn) {
    constexpr int P = 72;   // padded row (bf16 elems): 144B, 16B-aligned
    __shared__ __align__(16) ushort sQ[64 * P];
    __shared__ __align__(16) ushort sK[64 * P];
    __shared__ __align__(16) ushort sVt[64 * P];
    __shared__ __align__(16) ushort sP[4][16 * P];

    const int tx = threadIdx.x;
    const int w = tx >> 6;
    const int l = tx & 63;
    const int lr = l & 15, lq = l >> 4;
    const int qt = blockIdx.x;          // 0..31
    const int bh = blockIdx.y;          // 0..15
    const int b = bh >> 3, h = bh & 7;
    const size_t rowbase = (size_t)b * N_;
    const int qbase = qt * 64;

    // load Q tile (64 x 64)
    {
        int rr = tx >> 4;               // 0..15
        int c4 = (tx & 15) * 4;
#pragma unroll
        for (int p = 0; p < 4; ++p) {
            int r = rr + p * 16;
            const ushort* src = qkv + (rowbase + qbase + r) * QKVN_ + h * DH_ + c4;
            *(ushort4*)&sQ[r * P + c4] = *(const ushort4*)src;
        }
    }

    float m_i[4], l_i[4];
    floatx4 o[4] = {};
#pragma unroll
    for (int r = 0; r < 4; ++r) { m_i[r] = -1e30f; l_i[r] = 0.f; }

    for (int kt = 0; kt < 32; ++kt) {
        __syncthreads();
        // load K tile and V^T tile
        {
            int rr = tx >> 4;
            int c4 = (tx & 15) * 4;
#pragma unroll
            for (int p = 0; p < 4; ++p) {
                int kk = rr + p * 16;
                const ushort* srcK = qkv + (rowbase + kt * 64 + kk) * QKVN_ + INNER_ + h * DH_ + c4;
                *(ushort4*)&sK[kk * P + c4] = *(const ushort4*)srcK;
                const ushort* srcV = qkv + (rowbase + kt * 64 + kk) * QKVN_ + 2 * INNER_ + h * DH_ + c4;
                ushort4 v4 = *(const ushort4*)srcV;
                sVt[(c4 + 0) * P + kk] = v4.x;
                sVt[(c4 + 1) * P + kk] = v4.y;
                sVt[(c4 + 2) * P + kk] = v4.z;
                sVt[(c4 + 3) * P + kk] = v4.w;
            }
        }
        __syncthreads();

        // S = Q K^T : wave w owns rows 16w..16w+15, cols 0..63 (4 jt tiles)
        floatx4 c[4] = {};
        bf16x8 aq0 = *(const bf16x8*)&sQ[(16 * w + lr) * P + 8 * lq];
        bf16x8 aq1 = *(const bf16x8*)&sQ[(16 * w + lr) * P + 32 + 8 * lq];
#pragma unroll
        for (int jt = 0; jt < 4; ++jt) {
            bf16x8 bk0 = *(const bf16x8*)&sK[(16 * jt + lr) * P + 8 * lq];
            bf16x8 bk1 = *(const bf16x8*)&sK[(16 * jt + lr) * P + 32 + 8 * lq];
            c[jt] = __builtin_amdgcn_mfma_f32_16x16x32_bf16(aq0, bk0, c[jt], 0, 0, 0);
            c[jt] = __builtin_amdgcn_mfma_f32_16x16x32_bf16(aq1, bk1, c[jt], 0, 0, 0);
        }

        // online softmax; lane holds rows 4*lq+reg (C-layout), cols jt*16+lr
        float alpha[4];
#pragma unroll
        for (int reg = 0; reg < 4; ++reg) {
            float mx = fmaxf(fmaxf(c[0][reg], c[1][reg]), fmaxf(c[2][reg], c[3][reg]));
#pragma unroll
            for (int off = 1; off < 16; off <<= 1) mx = fmaxf(mx, __shfl_xor(mx, off));
            float mnew = fmaxf(m_i[reg], mx);
            alpha[reg] = __expf(m_i[reg] - mnew);
            m_i[reg] = mnew;
            float rs = 0.f;
#pragma unroll
            for (int jt = 0; jt < 4; ++jt) {
                float pv = __expf(c[jt][reg] - mnew);
                c[jt][reg] = pv;
                rs += pv;
            }
#pragma unroll
            for (int off = 1; off < 16; off <<= 1) rs += __shfl_xor(rs, off);
            l_i[reg] = l_i[reg] * alpha[reg] + rs;
        }

        // P -> LDS (per-wave region), rescale O
#pragma unroll
        for (int jt = 0; jt < 4; ++jt)
#pragma unroll
            for (int reg = 0; reg < 4; ++reg)
                sP[w][(4 * lq + reg) * P + jt * 16 + lr] = f2bf(c[jt][reg]);
#pragma unroll
        for (int dt = 0; dt < 4; ++dt)
#pragma unroll
            for (int reg = 0; reg < 4; ++reg) o[dt][reg] *= alpha[reg];

        // O += P @ V
        bf16x8 ap0 = *(const bf16x8*)&sP[w][lr * P + 8 * lq];
        bf16x8 ap1 = *(const bf16x8*)&sP[w][lr * P + 32 + 8 * lq];
#pragma unroll
        for (int dt = 0; dt < 4; ++dt) {
            bf16x8 bv0 = *(const bf16x8*)&sVt[(16 * dt + lr) * P + 8 * lq];
            bf16x8 bv1 = *(const bf16x8*)&sVt[(16 * dt + lr) * P + 32 + 8 * lq];
            o[dt] = __builtin_amdgcn_mfma_f32_16x16x32_bf16(ap0, bv0, o[dt], 0, 0, 0);
            o[dt] = __builtin_amdgcn_mfma_f32_16x16x32_bf16(ap1, bv1, o[dt], 0, 0, 0);
        }
    }

    // epilogue: O / l_i -> attn bf16
#pragma unroll
    for (int reg = 0; reg < 4; ++reg) {
        float inv = 1.f / l_i[reg];
        int row = qbase + 16 * w + 4 * lq + reg;
#pragma unroll
        for (int dt = 0; dt < 4; ++dt) {
            int col = h * DH_ + dt * 16 + lr;
            attn[(rowbase + row) * INNER_ + col] = f2bf(o[dt][reg] * inv);
        }
    }
}

// ---------------------------------------------------------------------------
extern "C" void kernel_launch(void* const* d_in, const int* in_sizes, int n_in,
                              void* d_out, int out_size, void* d_ws, size_t ws_size,
                              hipStream_t stream) {
    const float* x   = (const float*)d_in[0];
    const float* g   = (const float*)d_in[1];
    const float* wq  = (const float*)d_in[2];
    const float* wkv = (const float*)d_in[3];
    const float* wo  = (const float*)d_in[4];
    float* out = (float*)d_out;

    char* ws = (char*)d_ws;
    float*  psum   = (float*)(ws + 0);                  // 32*2048 f32 = 256KB
    float*  psqr   = (float*)(ws + 262144);             // 256KB
    float*  meanb  = (float*)(ws + 524288);             // 8KB
    float*  rstdb  = (float*)(ws + 532480);             // 8KB
    ushort* xn     = (ushort*)(ws + 540672);            // 4096x1024 bf16 = 8MB
    ushort* wqkv_t = (ushort*)(ws + 8929280);           // 1536x1024 bf16 = 3MB
    ushort* wo_t   = (ushort*)(ws + 12075008);          // 1024x512 bf16 = 1MB
    ushort* qkvb   = (ushort*)(ws + 13123584);          // 4096x1536 bf16 = 12MB
    ushort* attnb  = (ushort*)(ws + 25706496);          // 4096x512 bf16 = 4MB
    // total ~29.9 MB

    stats_partial<<<dim3(8, 32), 256, 0, stream>>>(x, psum, psqr);
    stats_final<<<8, 256, 0, stream>>>(psum, psqr, meanb, rstdb);
    norm_cast<<<4096, 256, 0, stream>>>(x, g, meanb, rstdb, xn);

    // wq -> rows [0,512) of wqkv_t, scaled by 1/8 (exact pow2 fold of q-scale)
    transpose_cast<<<dim3(32, 16), 256, 0, stream>>>(wq, wqkv_t, 1024, 512, 0.125f);
    transpose_cast<<<dim3(32, 32), 256, 0, stream>>>(wkv, wqkv_t + 512 * 1024, 1024, 1024, 1.0f);
    transpose_cast<<<dim3(16, 32), 256, 0, stream>>>(wo, wo_t, 512, 1024, 1.0f);

    gemm_bt<true><<<dim3(32, 12), 256, 0, stream>>>(xn, wqkv_t, qkvb, ROWS_, QKVN_, DIM_);
    flash_attn<<<dim3(32, 16), 256, 0, stream>>>(qkvb, attnb);
    gemm_bt<false><<<dim3(32, 8), 256, 0, stream>>>(attnb, wo_t, out, ROWS_, DIM_, INNER_);
}

// Round 2
// 175.752 us; speedup vs baseline: 1.5260x; 1.5260x over previous
//
#include <hip/hip_runtime.h>
#include <hip/hip_bf16.h>
#include <stdint.h>

// B=2, N=2048, DIM=1024, HEADS=8, DIM_HEAD=64, INNER=512
// LN(seq-axis stats) -> qkv GEMM -> V-transpose -> split-KV flash (no-max
// exp2 softmax, S^T trick) -> merge -> out GEMM. bf16 MFMA, fp32 accum.

#define B_ 2
#define N_ 2048
#define DIM_ 1024
#define DH_ 64
#define INNER_ 512
#define ROWS_ 4096
#define QKVN_ 1536

// q scale 1/8 (=DIM_HEAD^-0.5) * log2(e), folded into wq cast; kernel uses exp2.
#define QSCALE 0.18033688011112042f

typedef __bf16 bf16x8 __attribute__((ext_vector_type(8)));
typedef float floatx4 __attribute__((ext_vector_type(4)));

#if __has_builtin(__builtin_amdgcn_exp2f)
#define EXP2(x) __builtin_amdgcn_exp2f(x)
#else
#define EXP2(x) exp2f(x)
#endif

__device__ __forceinline__ ushort f2bf(float f) {
    union { float f; uint32_t u; } v; v.f = f;
    uint32_t u = v.u;
    u += 0x7fffu + ((u >> 16) & 1u);   // RNE
    return (ushort)(u >> 16);
}
__device__ __forceinline__ uint32_t pkbf(float a, float b) {
    return (uint32_t)f2bf(a) | ((uint32_t)f2bf(b) << 16);
}
__device__ __forceinline__ void gld_lds(const ushort* g, ushort* l) {
    __builtin_amdgcn_global_load_lds(
        (const __attribute__((address_space(1))) void*)g,
        (__attribute__((address_space(3))) void*)l, 16, 0, 0);
}

// ---------------------------------------------------------------------------
// K1: partial column stats over sequence axis. grid (8,32), block 256.
__global__ __launch_bounds__(256) void stats_partial(
    const float* __restrict__ x, float* __restrict__ ps, float* __restrict__ pq) {
    int gd = blockIdx.x * 256 + threadIdx.x;   // b*1024 + c
    int ch = blockIdx.y;
    int b = gd >> 10, c = gd & 1023;
    const float* p = x + (size_t)(b * N_ + ch * 64) * DIM_ + c;
    float s = 0.f, q = 0.f;
#pragma unroll 4
    for (int n = 0; n < 64; ++n) { float v = p[(size_t)n * DIM_]; s += v; q += v * v; }
    ps[ch * 2048 + gd] = s;
    pq[ch * 2048 + gd] = q;
}

// K2: finalize mean/rstd. grid 8, block 256.
__global__ __launch_bounds__(256) void stats_final(
    const float* __restrict__ ps, const float* __restrict__ pq,
    float* __restrict__ meanb, float* __restrict__ rstdb) {
    int gd = blockIdx.x * 256 + threadIdx.x;
    float s = 0.f, q = 0.f;
#pragma unroll
    for (int ch = 0; ch < 32; ++ch) { s += ps[ch * 2048 + gd]; q += pq[ch * 2048 + gd]; }
    float mean = s * (1.f / N_);
    float var = q * (1.f / N_) - mean * mean;
    meanb[gd] = mean;
    rstdb[gd] = rsqrtf(var + 1e-5f);
}

// K3: xn = (x - mean) * rstd * g, cast bf16. grid 4096, block 256.
__global__ __launch_bounds__(256) void norm_cast(
    const float* __restrict__ x, const float* __restrict__ g,
    const float* __restrict__ meanb, const float* __restrict__ rstdb,
    ushort* __restrict__ xn) {
    size_t e = ((size_t)blockIdx.x * 256 + threadIdx.x) * 4;
    int c = (int)(e & 1023);
    int b = (int)(e >> 21);            // e/(2048*1024)
    float4 xv = *(const float4*)&x[e];
    float4 gv = *(const float4*)&g[c];
    float4 mv = *(const float4*)&meanb[b * DIM_ + c];
    float4 rv = *(const float4*)&rstdb[b * DIM_ + c];
    ushort4 o;
    o.x = f2bf((xv.x - mv.x) * rv.x * gv.x);
    o.y = f2bf((xv.y - mv.y) * rv.y * gv.y);
    o.z = f2bf((xv.z - mv.z) * rv.z * gv.z);
    o.w = f2bf((xv.w - mv.w) * rv.w * gv.w);
    *(ushort4*)&xn[e] = o;
}

// K4: all three weight transposes fused in one launch. 2048 blocks.
__global__ __launch_bounds__(256) void transpose_all(
    const float* __restrict__ wq, const float* __restrict__ wkv,
    const float* __restrict__ wo, ushort* __restrict__ wqkv_t,
    ushort* __restrict__ wo_t) {
    __shared__ float tile[32][33];
    int bid = blockIdx.x;
    const float* src; ushort* dst; int C; int bx, by; float scale;
    if (bid < 512)       { src = wq;  dst = wqkv_t;              C = 512;  scale = QSCALE; bx = bid & 31; by = bid >> 5; }
    else if (bid < 1536) { int t = bid - 512;  src = wkv; dst = wqkv_t + 512 * 1024; C = 1024; scale = 1.f; bx = t & 31; by = t >> 5; }
    else                 { int t = bid - 1536; src = wo;  dst = wo_t;     C = 1024; scale = 1.f; bx = t & 15; by = t >> 4; }
    const int R = (bid >= 1536) ? 512 : 1024;  // src rows (= dst cols)
    int r0 = bx * 32, c0 = by * 32;
    int i = threadIdx.x >> 5, j = threadIdx.x & 31;
#pragma unroll
    for (int p = 0; p < 4; ++p)
        tile[i + 8 * p][j] = src[(size_t)(r0 + i + 8 * p) * C + c0 + j] * scale;
    __syncthreads();
#pragma unroll
    for (int p = 0; p < 4; ++p)
        dst[(size_t)(c0 + i + 8 * p) * R + r0 + j] = f2bf(tile[j][i + 8 * p]);
}

// ---------------------------------------------------------------------------
// K5: bf16 GEMM  C[M,N] = A[M,K] @ Bt[N,K]^T (unchanged from round 1).
template <bool OUT_BF16>
__global__ __launch_bounds__(256) void gemm_bt(
    const ushort* __restrict__ A, const ushort* __restrict__ Bt,
    void* __restrict__ C, int M, int N, int K) {
    __shared__ __align__(16) ushort sA[128 * 64];
    __shared__ __align__(16) ushort sB[128 * 64];
    const int tx = threadIdx.x;
    const int w = tx >> 6;
    const int l = tx & 63;
    const int tileM = blockIdx.x * 128;
    const int tileN = blockIdx.y * 128;
    const int wm = w & 1, wn = w >> 1;
    const int lr = l & 15, lq = l >> 4;
    const int srow = l >> 3;
    const int scol = (l & 7) * 8;

    floatx4 acc[4][4] = {};

    for (int k0 = 0; k0 < K; k0 += 64) {
#pragma unroll
        for (int c = 0; c < 4; ++c) {
            int rowA = tileM + 32 * w + 8 * c + srow;
            int rowB = tileN + 32 * w + 8 * c + srow;
            gld_lds(A + (size_t)rowA * K + k0 + scol, &sA[(32 * w + 8 * c) * 64]);
            gld_lds(Bt + (size_t)rowB * K + k0 + scol, &sB[(32 * w + 8 * c) * 64]);
        }
        __syncthreads();
#pragma unroll
        for (int s = 0; s < 2; ++s) {
            bf16x8 a[4], b[4];
#pragma unroll
            for (int mi = 0; mi < 4; ++mi)
                a[mi] = *(const bf16x8*)&sA[(64 * wm + 16 * mi + lr) * 64 + s * 32 + 8 * lq];
#pragma unroll
            for (int ni = 0; ni < 4; ++ni)
                b[ni] = *(const bf16x8*)&sB[(64 * wn + 16 * ni + lr) * 64 + s * 32 + 8 * lq];
#pragma unroll
            for (int mi = 0; mi < 4; ++mi)
#pragma unroll
                for (int ni = 0; ni < 4; ++ni)
                    acc[mi][ni] = __builtin_amdgcn_mfma_f32_16x16x32_bf16(
                        a[mi], b[ni], acc[mi][ni], 0, 0, 0);
        }
        __syncthreads();
    }

#pragma unroll
    for (int mi = 0; mi < 4; ++mi)
#pragma unroll
        for (int ni = 0; ni < 4; ++ni)
#pragma unroll
            for (int reg = 0; reg < 4; ++reg) {
                int row = tileM + 64 * wm + 16 * mi + 4 * lq + reg;
                int col = tileN + 64 * wn + 16 * ni + lr;
                float v = acc[mi][ni][reg];
                if (OUT_BF16)
                    ((ushort*)C)[(size_t)row * N + col] = f2bf(v);
                else
                    ((float*)C)[(size_t)row * N + col] = v;
            }
}

// ---------------------------------------------------------------------------
// K6: V transpose: qkvb v-part -> vT[bh][d][n]. grid (32, 16), block 256.
__global__ __launch_bounds__(256) void vtrans(
    const ushort* __restrict__ qkv, ushort* __restrict__ vT) {
    __shared__ __align__(16) ushort sT[64 * 72];
    int nt = blockIdx.x, bh = blockIdx.y;
    int b = bh >> 3, h = bh & 7;
    int tx = threadIdx.x;
#pragma unroll
    for (int p = 0; p < 2; ++p) {
        int idx = p * 256 + tx;
        int r = idx >> 3, ch = idx & 7;
        const ushort* gp = qkv + (size_t)(b * N_ + nt * 64 + r) * QKVN_ + 2 * INNER_ + h * DH_ + ch * 8;
        *(uint4*)&sT[r * 72 + ch * 8] = *(const uint4*)gp;
    }
    __syncthreads();
#pragma unroll
    for (int p = 0; p < 2; ++p) {
        int idx = p * 256 + tx;
        int d = idx >> 3, c8 = (idx & 7) * 8;
        union { ushort us[8]; uint4 v; } t;
#pragma unroll
        for (int i = 0; i < 8; ++i) t.us[i] = sT[(c8 + i) * 72 + d];
        *(uint4*)&vT[((size_t)bh * DH_ + d) * N_ + nt * 64 + c8] = t.v;
    }
}

// ---------------------------------------------------------------------------
// K7: split-KV flash. grid (16 qtiles-of-128, 16 bh, nsplit). block 256 =
// 4 waves x 32 q-rows. No-max exp2 softmax (scores provably bounded).
// S computed TRANSPOSED (A=K, B=Q) so lanes hold consecutive keys per q-row:
// packed b64 P-stores + deferred 2-shuffle l-reduction. XOR-swizzled
// global_load_lds staging for conflict-free b128 frag reads.
__global__ __launch_bounds__(256, 4) void flash_attn(
    const ushort* __restrict__ qkv, const ushort* __restrict__ vT,
    float* __restrict__ po0, float* __restrict__ po1,
    float* __restrict__ pl, int nkt) {
    __shared__ __align__(16) ushort sK[64 * 64];
    __shared__ __align__(16) ushort sV[64 * 64];
    __shared__ __align__(16) ushort sPQ[4 * 32 * 72];  // sQ(128x64, stride 64) alias / per-wave P(32x72)

    const int tx = threadIdx.x;
    const int w = tx >> 6, l = tx & 63;
    const int lr = l & 15, lq = l >> 4;
    const int qt = blockIdx.x, bh = blockIdx.y, sp = blockIdx.z;
    const int b = bh >> 3, h = bh & 7;
    const size_t rowbase = (size_t)b * N_;
    const int qbase = qt * 128;
    const int kbase = sp * nkt * 64;

    const int rl = l >> 3;              // row within 8-row staging group
    const int swz = (l & 7) ^ rl;       // swizzled source chunk for staging
    const int fr0 = ((0 + lq) ^ (lr & 7)) * 8;  // frag-read offsets (elems)
    const int fr1 = ((4 + lq) ^ (lr & 7)) * 8;

    // stage Q (128 rows x 64) into sPQ with row stride 64
#pragma unroll
    for (int i = 0; i < 4; ++i) {
        int r0 = 32 * w + 8 * i;
        gld_lds(qkv + (rowbase + qbase + r0 + rl) * QKVN_ + h * DH_ + swz * 8,
                &sPQ[r0 * 64]);
    }
    __syncthreads();
    // hoist Q frags (B operand): rows 32w+16qq+lr
    bf16x8 bq[2][2];
#pragma unroll
    for (int qq = 0; qq < 2; ++qq) {
        int r = (32 * w + 16 * qq + lr) * 64;
        bq[qq][0] = *(const bf16x8*)&sPQ[r + fr0];
        bq[qq][1] = *(const bf16x8*)&sPQ[r + fr1];
    }

    floatx4 o[2][4] = {};
    float lsum[2] = {0.f, 0.f};

    for (int kt = 0; kt < nkt; ++kt) {
        __syncthreads();   // prior reads of sK/sV done; Q-frag reads done (kt=0)
#pragma unroll
        for (int i = 0; i < 2; ++i) {
            int r0 = 16 * w + 8 * i;
            gld_lds(qkv + (rowbase + kbase + kt * 64 + r0 + rl) * QKVN_ + INNER_ + h * DH_ + swz * 8,
                    &sK[r0 * 64]);
            gld_lds(vT + ((size_t)bh * DH_ + r0 + rl) * N_ + kbase + kt * 64 + swz * 8,
                    &sV[r0 * 64]);
        }
        __syncthreads();

        // S^T = K . Q^T : c[kk][qq], rows=keys, cols=q
        floatx4 c[4][2] = {};
#pragma unroll
        for (int s = 0; s < 2; ++s) {
            const int fo = s ? fr1 : fr0;
            bf16x8 ak[4];
#pragma unroll
            for (int kk = 0; kk < 4; ++kk)
                ak[kk] = *(const bf16x8*)&sK[(16 * kk + lr) * 64 + fo];
#pragma unroll
            for (int kk = 0; kk < 4; ++kk)
#pragma unroll
                for (int qq = 0; qq < 2; ++qq)
                    c[kk][qq] = __builtin_amdgcn_mfma_f32_16x16x32_bf16(
                        ak[kk], bq[qq][s], c[kk][qq], 0, 0, 0);
        }

        // exp2, accumulate row-sums, pack pairs of consecutive keys -> P rows
#pragma unroll
        for (int kk = 0; kk < 4; ++kk)
#pragma unroll
            for (int qq = 0; qq < 2; ++qq) {
                float e0 = EXP2(c[kk][qq][0]);
                float e1 = EXP2(c[kk][qq][1]);
                float e2 = EXP2(c[kk][qq][2]);
                float e3 = EXP2(c[kk][qq][3]);
                lsum[qq] += (e0 + e1) + (e2 + e3);
                uint2 u; u.x = pkbf(e0, e1); u.y = pkbf(e2, e3);
                // P[q=16qq+lr][keys 16kk+4lq .. +3], per-wave region, pad 72
                *(uint2*)&sPQ[(32 * w + 16 * qq + lr) * 72 + 16 * kk + 4 * lq] = u;
            }

        // O[q][d] += P @ V  (A=P rows q, B=V^T rows d, k=keys)
#pragma unroll
        for (int s = 0; s < 2; ++s) {
            const int fo = s ? fr1 : fr0;
            bf16x8 ap[2], bv[4];
#pragma unroll
            for (int mi = 0; mi < 2; ++mi)
                ap[mi] = *(const bf16x8*)&sPQ[(32 * w + 16 * mi + lr) * 72 + 32 * s + 8 * lq];
#pragma unroll
            for (int dt = 0; dt < 4; ++dt)
                bv[dt] = *(const bf16x8*)&sV[(16 * dt + lr) * 64 + fo];
#pragma unroll
            for (int mi = 0; mi < 2; ++mi)
#pragma unroll
                for (int dt = 0; dt < 4; ++dt)
                    o[mi][dt] = __builtin_amdgcn_mfma_f32_16x16x32_bf16(
                        ap[mi], bv[dt], o[mi][dt], 0, 0, 0);
        }
    }

    // deferred l reduction across lq groups (keys partition)
#pragma unroll
    for (int qq = 0; qq < 2; ++qq) {
        lsum[qq] += __shfl_xor(lsum[qq], 16);
        lsum[qq] += __shfl_xor(lsum[qq], 32);
    }
    float* po = sp ? po1 : po0;
    if (lq == 0) {
#pragma unroll
        for (int qq = 0; qq < 2; ++qq)
            pl[((size_t)sp * 16 + bh) * N_ + qbase + 32 * w + 16 * qq + lr] = lsum[qq];
    }
    const size_t obase = (size_t)bh * N_;
#pragma unroll
    for (int mi = 0; mi < 2; ++mi)
#pragma unroll
        for (int dt = 0; dt < 4; ++dt)
#pragma unroll
            for (int reg = 0; reg < 4; ++reg) {
                int row = qbase + 32 * w + 16 * mi + 4 * lq + reg;
                po[(obase + row) * DH_ + 16 * dt + lr] = o[mi][dt][reg];
            }
}

// K8: merge splits + normalize + cast. grid 2048, block 256.
__global__ __launch_bounds__(256) void merge_attn(
    const float* __restrict__ po0, const float* __restrict__ po1,
    const float* __restrict__ pl, ushort* __restrict__ attn, int nsplit) {
    int idx = blockIdx.x * 256 + threadIdx.x;
    int d4 = (idx & 15) * 4;
    int h = (idx >> 4) & 7;
    int rowg = idx >> 7;               // 0..4095
    int b = rowg >> 11, r = rowg & 2047;
    size_t pbase = ((size_t)b * 8 + h) * N_ + r;
    float4 acc = *(const float4*)&po0[pbase * DH_ + d4];
    float lv = pl[pbase];
    if (nsplit == 2) {
        float4 a1 = *(const float4*)&po1[pbase * DH_ + d4];
        acc.x += a1.x; acc.y += a1.y; acc.z += a1.z; acc.w += a1.w;
        lv += pl[(size_t)16 * N_ + pbase];
    }
    float inv = 1.f / lv;
    ushort4 ov;
    ov.x = f2bf(acc.x * inv); ov.y = f2bf(acc.y * inv);
    ov.z = f2bf(acc.z * inv); ov.w = f2bf(acc.w * inv);
    *(ushort4*)&attn[(size_t)rowg * INNER_ + h * DH_ + d4] = ov;
}

// ---------------------------------------------------------------------------
extern "C" void kernel_launch(void* const* d_in, const int* in_sizes, int n_in,
                              void* d_out, int out_size, void* d_ws, size_t ws_size,
                              hipStream_t stream) {
    const float* x   = (const float*)d_in[0];
    const float* g   = (const float*)d_in[1];
    const float* wq  = (const float*)d_in[2];
    const float* wkv = (const float*)d_in[3];
    const float* wo  = (const float*)d_in[4];
    float* out = (float*)d_out;

    char* ws = (char*)d_ws;
    float*  psum   = (float*)(ws + 0);          // 256K   (dead after stats_final)
    float*  psqr   = (float*)(ws + 262144);     // 256K
    float*  meanb  = (float*)(ws + 524288);     // 8K
    float*  rstdb  = (float*)(ws + 532480);     // 8K
    ushort* xn     = (ushort*)(ws + 540672);    // 8.39M  (dead after gemm1)
    ushort* wqkv_t = (ushort*)(ws + 8929280);   // 3.15M
    ushort* wo_t   = (ushort*)(ws + 12075008);  // 1.05M
    ushort* qkvb   = (ushort*)(ws + 13123584);  // 12.58M
    ushort* attnb  = (ushort*)(ws + 25706496);  // 4.19M
    ushort* vTb    = (ushort*)(ws + 29900800);  // 4.19M
    float*  plb    = (float*)(ws + 34095104);   // 256K
    float*  po0    = (float*)(ws + 0);          // 8.39M overlays dead stats+xn
    float*  po1    = (float*)(ws + 34357248);   // 8.39M (split 2 only) -> end 42.75M

    const int nsplit = (ws_size >= (size_t)45 * 1024 * 1024) ? 2 : 1;

    stats_partial<<<dim3(8, 32), 256, 0, stream>>>(x, psum, psqr);
    stats_final<<<8, 256, 0, stream>>>(psum, psqr, meanb, rstdb);
    norm_cast<<<4096, 256, 0, stream>>>(x, g, meanb, rstdb, xn);
    transpose_all<<<2048, 256, 0, stream>>>(wq, wkv, wo, wqkv_t, wo_t);

    gemm_bt<true><<<dim3(32, 12), 256, 0, stream>>>(xn, wqkv_t, qkvb, ROWS_, QKVN_, DIM_);
    vtrans<<<dim3(32, 16), 256, 0, stream>>>(qkvb, vTb);
    flash_attn<<<dim3(16, 16, nsplit), 256, 0, stream>>>(qkvb, vTb, po0, po1, plb, 32 / nsplit);
    merge_attn<<<2048, 256, 0, stream>>>(po0, po1, plb, attnb, nsplit);
    gemm_bt<false><<<dim3(32, 8), 256, 0, stream>>>(attnb, wo_t, out, ROWS_, DIM_, INNER_);
}

// Round 3
// 161.763 us; speedup vs baseline: 1.6580x; 1.0865x over previous
//
#include <hip/hip_runtime.h>
#include <hip/hip_bf16.h>
#include <stdint.h>

// B=2, N=2048, DIM=1024, HEADS=8, DIM_HEAD=64, INNER=512
// LN(seq-axis stats) -> qkv GEMM -> V-transpose -> split-KV flash (no-max
// exp2 softmax, S^T trick) -> merge -> out GEMM. bf16 MFMA, fp32 accum.
// Round 3: 64-row GEMM tiles (3-4 blocks/CU), XOR-swizzled GEMM LDS,
// flash nsplit=4, fused setup kernel.

#define B_ 2
#define N_ 2048
#define DIM_ 1024
#define DH_ 64
#define INNER_ 512
#define ROWS_ 4096
#define QKVN_ 1536
#define POSTRIDE 2097152   // 16*2048*64 floats per split

// q scale 1/8 (=DH^-0.5) * log2(e), folded into wq cast; kernel uses exp2.
#define QSCALE 0.18033688011112042f

typedef __bf16 bf16x8 __attribute__((ext_vector_type(8)));
typedef float floatx4 __attribute__((ext_vector_type(4)));

#if __has_builtin(__builtin_amdgcn_exp2f)
#define EXP2(x) __builtin_amdgcn_exp2f(x)
#else
#define EXP2(x) exp2f(x)
#endif

__device__ __forceinline__ ushort f2bf(float f) {
    union { float f; uint32_t u; } v; v.f = f;
    uint32_t u = v.u;
    u += 0x7fffu + ((u >> 16) & 1u);   // RNE
    return (ushort)(u >> 16);
}
__device__ __forceinline__ uint32_t pkbf(float a, float b) {
    return (uint32_t)f2bf(a) | ((uint32_t)f2bf(b) << 16);
}
__device__ __forceinline__ void gld_lds(const ushort* g, ushort* l) {
    __builtin_amdgcn_global_load_lds(
        (const __attribute__((address_space(1))) void*)g,
        (__attribute__((address_space(3))) void*)l, 16, 0, 0);
}

// ---------------------------------------------------------------------------
// K1: fused setup: blocks 0..255 = partial column stats (seq axis);
// blocks 256..2303 = weight transpose+cast. Independent work, one launch.
__global__ __launch_bounds__(256) void setup_fused(
    const float* __restrict__ x, float* __restrict__ ps, float* __restrict__ pq,
    const float* __restrict__ wq, const float* __restrict__ wkv,
    const float* __restrict__ wo, ushort* __restrict__ wqkv_t,
    ushort* __restrict__ wo_t) {
    __shared__ float tile[32][33];
    int bid = blockIdx.x;
    if (bid < 256) {
        int gd = (bid & 7) * 256 + threadIdx.x;   // b*1024 + c
        int ch = bid >> 3;                        // 0..31
        int b = gd >> 10;
        const float* p = x + (size_t)(b * N_ + ch * 64) * DIM_ + (gd & 1023);
        float s = 0.f, q = 0.f;
#pragma unroll 4
        for (int n = 0; n < 64; ++n) { float v = p[(size_t)n * DIM_]; s += v; q += v * v; }
        ps[ch * 2048 + gd] = s;
        pq[ch * 2048 + gd] = q;
        return;
    }
    int t = bid - 256;
    const float* src; ushort* dst; int C; int bx, by; float scale;
    if (t < 512)       { src = wq;  dst = wqkv_t;              C = 512;  scale = QSCALE; bx = t & 31; by = t >> 5; }
    else if (t < 1536) { int u = t - 512;  src = wkv; dst = wqkv_t + 512 * 1024; C = 1024; scale = 1.f; bx = u & 31; by = u >> 5; }
    else               { int u = t - 1536; src = wo;  dst = wo_t;       C = 1024; scale = 1.f; bx = u & 15; by = u >> 4; }
    const int R = (t >= 1536) ? 512 : 1024;   // src rows (= dst cols)
    int r0 = bx * 32, c0 = by * 32;
    int i = threadIdx.x >> 5, j = threadIdx.x & 31;
#pragma unroll
    for (int p = 0; p < 4; ++p)
        tile[i + 8 * p][j] = src[(size_t)(r0 + i + 8 * p) * C + c0 + j] * scale;
    __syncthreads();
#pragma unroll
    for (int p = 0; p < 4; ++p)
        dst[(size_t)(c0 + i + 8 * p) * R + r0 + j] = f2bf(tile[j][i + 8 * p]);
}

// K2: finalize mean/rstd. grid 8, block 256.
__global__ __launch_bounds__(256) void stats_final(
    const float* __restrict__ ps, const float* __restrict__ pq,
    float* __restrict__ meanb, float* __restrict__ rstdb) {
    int gd = blockIdx.x * 256 + threadIdx.x;
    float s = 0.f, q = 0.f;
#pragma unroll
    for (int ch = 0; ch < 32; ++ch) { s += ps[ch * 2048 + gd]; q += pq[ch * 2048 + gd]; }
    float mean = s * (1.f / N_);
    float var = q * (1.f / N_) - mean * mean;
    meanb[gd] = mean;
    rstdb[gd] = rsqrtf(var + 1e-5f);
}

// K3: xn = (x - mean) * rstd * g, cast bf16. grid 4096, block 256.
__global__ __launch_bounds__(256) void norm_cast(
    const float* __restrict__ x, const float* __restrict__ g,
    const float* __restrict__ meanb, const float* __restrict__ rstdb,
    ushort* __restrict__ xn) {
    size_t e = ((size_t)blockIdx.x * 256 + threadIdx.x) * 4;
    int c = (int)(e & 1023);
    int b = (int)(e >> 21);
    float4 xv = *(const float4*)&x[e];
    float4 gv = *(const float4*)&g[c];
    float4 mv = *(const float4*)&meanb[b * DIM_ + c];
    float4 rv = *(const float4*)&rstdb[b * DIM_ + c];
    ushort4 o;
    o.x = f2bf((xv.x - mv.x) * rv.x * gv.x);
    o.y = f2bf((xv.y - mv.y) * rv.y * gv.y);
    o.z = f2bf((xv.z - mv.z) * rv.z * gv.z);
    o.w = f2bf((xv.w - mv.w) * rv.w * gv.w);
    *(ushort4*)&xn[e] = o;
}

// ---------------------------------------------------------------------------
// K4: bf16 GEMM  C[M,N] = A[M,K] @ Bt[N,K]^T.  64 x (32*NI) tile, 4 waves
// (2x2), wave = 32 x (16*NI). BK=64, global_load_lds, XOR chunk swizzle so
// frag b128 reads hit all 32 banks (2-way = free).
template <int NI, bool OUT_BF16>
__global__ __launch_bounds__(256) void gemm_bt(
    const ushort* __restrict__ A, const ushort* __restrict__ Bt,
    void* __restrict__ C, int M, int N, int K) {
    constexpr int TN = 32 * NI;
    __shared__ __align__(16) ushort sA[64 * 64];
    __shared__ __align__(16) ushort sB[TN * 64];
    const int tx = threadIdx.x;
    const int w = tx >> 6, l = tx & 63;
    const int wm = w & 1, wn = w >> 1;
    const int lr = l & 15, lq = l >> 4;
    const int tileM = blockIdx.x * 64;
    const int tileN = blockIdx.y * TN;
    const int rl = l >> 3;
    const int swz8 = ((l & 7) ^ rl) * 8;        // swizzled source chunk (elems)
    const int fo0 = (lq ^ (lr & 7)) * 8;        // frag-read offsets (elems)
    const int fo1 = ((4 + lq) ^ (lr & 7)) * 8;

    floatx4 acc[2][NI] = {};

    for (int k0 = 0; k0 < K; k0 += 64) {
#pragma unroll
        for (int i = 0; i < 2; ++i) {
            int r0 = 16 * w + 8 * i;
            gld_lds(A + (size_t)(tileM + r0 + rl) * K + k0 + swz8, &sA[r0 * 64]);
        }
#pragma unroll
        for (int i = 0; i < TN / 32; ++i) {
            int r0 = (TN / 4) * w + 8 * i;
            gld_lds(Bt + (size_t)(tileN + r0 + rl) * K + k0 + swz8, &sB[r0 * 64]);
        }
        __syncthreads();
#pragma unroll
        for (int s = 0; s < 2; ++s) {
            const int fo = s ? fo1 : fo0;
            bf16x8 a[2], b[NI];
#pragma unroll
            for (int mi = 0; mi < 2; ++mi)
                a[mi] = *(const bf16x8*)&sA[(32 * wm + 16 * mi + lr) * 64 + fo];
#pragma unroll
            for (int ni = 0; ni < NI; ++ni)
                b[ni] = *(const bf16x8*)&sB[(16 * NI * wn + 16 * ni + lr) * 64 + fo];
#pragma unroll
            for (int mi = 0; mi < 2; ++mi)
#pragma unroll
                for (int ni = 0; ni < NI; ++ni)
                    acc[mi][ni] = __builtin_amdgcn_mfma_f32_16x16x32_bf16(
                        a[mi], b[ni], acc[mi][ni], 0, 0, 0);
        }
        __syncthreads();
    }

#pragma unroll
    for (int mi = 0; mi < 2; ++mi)
#pragma unroll
        for (int ni = 0; ni < NI; ++ni)
#pragma unroll
            for (int reg = 0; reg < 4; ++reg) {
                int row = tileM + 32 * wm + 16 * mi + 4 * lq + reg;
                int col = tileN + 16 * NI * wn + 16 * ni + lr;
                float v = acc[mi][ni][reg];
                if (OUT_BF16)
                    ((ushort*)C)[(size_t)row * N + col] = f2bf(v);
                else
                    ((float*)C)[(size_t)row * N + col] = v;
            }
}

// ---------------------------------------------------------------------------
// K5: V transpose: qkvb v-part -> vT[bh][d][n]. grid (32, 16), block 256.
__global__ __launch_bounds__(256) void vtrans(
    const ushort* __restrict__ qkv, ushort* __restrict__ vT) {
    __shared__ __align__(16) ushort sT[64 * 72];
    int nt = blockIdx.x, bh = blockIdx.y;
    int b = bh >> 3, h = bh & 7;
    int tx = threadIdx.x;
#pragma unroll
    for (int p = 0; p < 2; ++p) {
        int idx = p * 256 + tx;
        int r = idx >> 3, ch = idx & 7;
        const ushort* gp = qkv + (size_t)(b * N_ + nt * 64 + r) * QKVN_ + 2 * INNER_ + h * DH_ + ch * 8;
        *(uint4*)&sT[r * 72 + ch * 8] = *(const uint4*)gp;
    }
    __syncthreads();
#pragma unroll
    for (int p = 0; p < 2; ++p) {
        int idx = p * 256 + tx;
        int d = idx >> 3, c8 = (idx & 7) * 8;
        union { ushort us[8]; uint4 v; } t;
#pragma unroll
        for (int i = 0; i < 8; ++i) t.us[i] = sT[(c8 + i) * 72 + d];
        *(uint4*)&vT[((size_t)bh * DH_ + d) * N_ + nt * 64 + c8] = t.v;
    }
}

// ---------------------------------------------------------------------------
// K6: split-KV flash. grid (16 qtiles-of-128, 16 bh, nsplit). block 256 =
// 4 waves x 32 q-rows. No-max exp2 softmax (scores provably bounded).
// S computed TRANSPOSED (A=K, B=Q): packed b64 P-stores + deferred
// 2-shuffle l-reduction. XOR-swizzled global_load_lds staging.
__global__ __launch_bounds__(256, 4) void flash_attn(
    const ushort* __restrict__ qkv, const ushort* __restrict__ vT,
    float* __restrict__ po, float* __restrict__ pl, int nkt) {
    __shared__ __align__(16) ushort sK[64 * 64];
    __shared__ __align__(16) ushort sV[64 * 64];
    __shared__ __align__(16) ushort sPQ[4 * 32 * 72];  // Q(128x64 s64) alias / per-wave P(32x72)

    const int tx = threadIdx.x;
    const int w = tx >> 6, l = tx & 63;
    const int lr = l & 15, lq = l >> 4;
    const int qt = blockIdx.x, bh = blockIdx.y, sp = blockIdx.z;
    const int b = bh >> 3, h = bh & 7;
    const size_t rowbase = (size_t)b * N_;
    const int qbase = qt * 128;
    const int kbase = sp * nkt * 64;

    const int rl = l >> 3;
    const int swz8 = ((l & 7) ^ rl) * 8;
    const int fr0 = (lq ^ (lr & 7)) * 8;
    const int fr1 = ((4 + lq) ^ (lr & 7)) * 8;

    // stage Q (128 rows x 64) into sPQ with row stride 64
#pragma unroll
    for (int i = 0; i < 4; ++i) {
        int r0 = 32 * w + 8 * i;
        gld_lds(qkv + (rowbase + qbase + r0 + rl) * QKVN_ + h * DH_ + swz8,
                &sPQ[r0 * 64]);
    }
    __syncthreads();
    bf16x8 bq[2][2];
#pragma unroll
    for (int qq = 0; qq < 2; ++qq) {
        int r = (32 * w + 16 * qq + lr) * 64;
        bq[qq][0] = *(const bf16x8*)&sPQ[r + fr0];
        bq[qq][1] = *(const bf16x8*)&sPQ[r + fr1];
    }

    floatx4 o[2][4] = {};
    float lsum[2] = {0.f, 0.f};

    for (int kt = 0; kt < nkt; ++kt) {
        __syncthreads();
#pragma unroll
        for (int i = 0; i < 2; ++i) {
            int r0 = 16 * w + 8 * i;
            gld_lds(qkv + (rowbase + kbase + kt * 64 + r0 + rl) * QKVN_ + INNER_ + h * DH_ + swz8,
                    &sK[r0 * 64]);
            gld_lds(vT + ((size_t)bh * DH_ + r0 + rl) * N_ + kbase + kt * 64 + swz8,
                    &sV[r0 * 64]);
        }
        __syncthreads();

        // S^T = K . Q^T : c[kk][qq], rows=keys, cols=q
        floatx4 c[4][2] = {};
#pragma unroll
        for (int s = 0; s < 2; ++s) {
            const int fo = s ? fr1 : fr0;
            bf16x8 ak[4];
#pragma unroll
            for (int kk = 0; kk < 4; ++kk)
                ak[kk] = *(const bf16x8*)&sK[(16 * kk + lr) * 64 + fo];
#pragma unroll
            for (int kk = 0; kk < 4; ++kk)
#pragma unroll
                for (int qq = 0; qq < 2; ++qq)
                    c[kk][qq] = __builtin_amdgcn_mfma_f32_16x16x32_bf16(
                        ak[kk], bq[qq][s], c[kk][qq], 0, 0, 0);
        }

        // exp2, accumulate row-sums, pack consecutive-key pairs -> P rows
#pragma unroll
        for (int kk = 0; kk < 4; ++kk)
#pragma unroll
            for (int qq = 0; qq < 2; ++qq) {
                float e0 = EXP2(c[kk][qq][0]);
                float e1 = EXP2(c[kk][qq][1]);
                float e2 = EXP2(c[kk][qq][2]);
                float e3 = EXP2(c[kk][qq][3]);
                lsum[qq] += (e0 + e1) + (e2 + e3);
                uint2 u; u.x = pkbf(e0, e1); u.y = pkbf(e2, e3);
                *(uint2*)&sPQ[(32 * w + 16 * qq + lr) * 72 + 16 * kk + 4 * lq] = u;
            }

        // O[q][d] += P @ V
#pragma unroll
        for (int s = 0; s < 2; ++s) {
            const int fo = s ? fr1 : fr0;
            bf16x8 ap[2], bv[4];
#pragma unroll
            for (int mi = 0; mi < 2; ++mi)
                ap[mi] = *(const bf16x8*)&sPQ[(32 * w + 16 * mi + lr) * 72 + 32 * s + 8 * lq];
#pragma unroll
            for (int dt = 0; dt < 4; ++dt)
                bv[dt] = *(const bf16x8*)&sV[(16 * dt + lr) * 64 + fo];
#pragma unroll
            for (int mi = 0; mi < 2; ++mi)
#pragma unroll
                for (int dt = 0; dt < 4; ++dt)
                    o[mi][dt] = __builtin_amdgcn_mfma_f32_16x16x32_bf16(
                        ap[mi], bv[dt], o[mi][dt], 0, 0, 0);
        }
    }

#pragma unroll
    for (int qq = 0; qq < 2; ++qq) {
        lsum[qq] += __shfl_xor(lsum[qq], 16);
        lsum[qq] += __shfl_xor(lsum[qq], 32);
    }
    float* pob = po + (size_t)sp * POSTRIDE;
    if (lq == 0) {
#pragma unroll
        for (int qq = 0; qq < 2; ++qq)
            pl[((size_t)sp * 16 + bh) * N_ + qbase + 32 * w + 16 * qq + lr] = lsum[qq];
    }
    const size_t obase = (size_t)bh * N_;
#pragma unroll
    for (int mi = 0; mi < 2; ++mi)
#pragma unroll
        for (int dt = 0; dt < 4; ++dt)
#pragma unroll
            for (int reg = 0; reg < 4; ++reg) {
                int row = qbase + 32 * w + 16 * mi + 4 * lq + reg;
                pob[(obase + row) * DH_ + 16 * dt + lr] = o[mi][dt][reg];
            }
}

// K7: merge splits + normalize + cast. grid 2048, block 256.
__global__ __launch_bounds__(256) void merge_attn(
    const float* __restrict__ po, const float* __restrict__ pl,
    ushort* __restrict__ attn, int nsplit) {
    int idx = blockIdx.x * 256 + threadIdx.x;
    int d4 = (idx & 15) * 4;
    int h = (idx >> 4) & 7;
    int rowg = idx >> 7;
    int b = rowg >> 11, r = rowg & 2047;
    size_t pbase = ((size_t)b * 8 + h) * N_ + r;
    float4 acc = *(const float4*)&po[pbase * DH_ + d4];
    float lv = pl[pbase];
    for (int s = 1; s < nsplit; ++s) {
        float4 a1 = *(const float4*)&po[(size_t)s * POSTRIDE + pbase * DH_ + d4];
        acc.x += a1.x; acc.y += a1.y; acc.z += a1.z; acc.w += a1.w;
        lv += pl[((size_t)s * 16) * N_ + pbase];
    }
    float inv = 1.f / lv;
    ushort4 ov;
    ov.x = f2bf(acc.x * inv); ov.y = f2bf(acc.y * inv);
    ov.z = f2bf(acc.z * inv); ov.w = f2bf(acc.w * inv);
    *(ushort4*)&attn[(size_t)rowg * INNER_ + h * DH_ + d4] = ov;
}

// ---------------------------------------------------------------------------
extern "C" void kernel_launch(void* const* d_in, const int* in_sizes, int n_in,
                              void* d_out, int out_size, void* d_ws, size_t ws_size,
                              hipStream_t stream) {
    const float* x   = (const float*)d_in[0];
    const float* g   = (const float*)d_in[1];
    const float* wq  = (const float*)d_in[2];
    const float* wkv = (const float*)d_in[3];
    const float* wo  = (const float*)d_in[4];
    float* out = (float*)d_out;

    char* ws = (char*)d_ws;
    float*  psum   = (float*)(ws + 0);          // 256K
    float*  psqr   = (float*)(ws + 262144);     // 256K
    float*  meanb  = (float*)(ws + 524288);     // 8K
    float*  rstdb  = (float*)(ws + 532480);     // 8K
    ushort* xn     = (ushort*)(ws + 540672);    // 8.39M
    ushort* wqkv_t = (ushort*)(ws + 8929280);   // 3.15M
    ushort* wo_t   = (ushort*)(ws + 12075008);  // 1.05M
    ushort* qkvb   = (ushort*)(ws + 13123584);  // 12.58M
    ushort* attnb  = (ushort*)(ws + 25706496);  // 4.19M
    ushort* vTb    = (ushort*)(ws + 29900800);  // 4.19M
    float*  plb    = (float*)(ws + 34095104);   // 512K (4 splits x 16 x 2048)
    float*  pob    = (float*)(ws + 34619392);   // up to 4 x 8.39M -> end 68.2M

    const int nsplit = (ws_size >= (size_t)70 * 1024 * 1024) ? 4
                     : (ws_size >= (size_t)52 * 1024 * 1024) ? 2 : 1;

    setup_fused<<<2304, 256, 0, stream>>>(x, psum, psqr, wq, wkv, wo, wqkv_t, wo_t);
    stats_final<<<8, 256, 0, stream>>>(psum, psqr, meanb, rstdb);
    norm_cast<<<4096, 256, 0, stream>>>(x, g, meanb, rstdb, xn);

    gemm_bt<4, true><<<dim3(64, 12), 256, 0, stream>>>(xn, wqkv_t, qkvb, ROWS_, QKVN_, DIM_);
    vtrans<<<dim3(32, 16), 256, 0, stream>>>(qkvb, vTb);
    flash_attn<<<dim3(16, 16, nsplit), 256, 0, stream>>>(qkvb, vTb, pob, plb, 32 / nsplit);
    merge_attn<<<2048, 256, 0, stream>>>(pob, plb, attnb, nsplit);
    gemm_bt<2, false><<<dim3(64, 16), 256, 0, stream>>>(attnb, wo_t, out, ROWS_, DIM_, INNER_);
}

// Round 4
// 158.800 us; speedup vs baseline: 1.6889x; 1.0187x over previous
//
#include <hip/hip_runtime.h>
#include <hip/hip_bf16.h>
#include <stdint.h>

// B=2, N=2048, DIM=1024, HEADS=8, DIM_HEAD=64, INNER=512
// Round 4: LDS-free GEMMs. Producers (norm / setup / merge) write operands in
// MFMA frag-major layout [mtile16][kchunk32][lane64][8]; GEMM K-loops load
// frags straight to VGPRs (no LDS, no barriers) with a 2-stage reg pipeline.
// gemm1 epilogue writes V transposed (vtrans fused); stats_final fused into
// norm. 6 kernels total.

#define B_ 2
#define N_ 2048
#define DIM_ 1024
#define DH_ 64
#define INNER_ 512
#define ROWS_ 4096
#define POSTRIDE 2097152   // 16*2048*64 floats per split

// q scale 1/8 (=DH^-0.5) * log2(e), folded into wq cast; kernel uses exp2.
#define QSCALE 0.18033688011112042f

typedef __bf16 bf16x8 __attribute__((ext_vector_type(8)));
typedef float floatx4 __attribute__((ext_vector_type(4)));

#if __has_builtin(__builtin_amdgcn_exp2f)
#define EXP2(x) __builtin_amdgcn_exp2f(x)
#else
#define EXP2(x) exp2f(x)
#endif

__device__ __forceinline__ ushort f2bf(float f) {
    union { float f; uint32_t u; } v; v.f = f;
    uint32_t u = v.u;
    u += 0x7fffu + ((u >> 16) & 1u);   // RNE
    return (ushort)(u >> 16);
}
__device__ __forceinline__ uint32_t pkbf(float a, float b) {
    return (uint32_t)f2bf(a) | ((uint32_t)f2bf(b) << 16);
}
__device__ __forceinline__ void gld_lds(const ushort* g, ushort* l) {
    __builtin_amdgcn_global_load_lds(
        (const __attribute__((address_space(1))) void*)g,
        (__attribute__((address_space(3))) void*)l, 16, 0, 0);
}
// frag-major element offset: lane l of a wave holds M=16*T+(l&15),
// k = 32*kc + 8*(l>>4) + j  (j=0..7). nkc = K/32.
__device__ __forceinline__ size_t frag_off(int m, int k, int nkc) {
    return ((size_t)((m >> 4) * nkc + (k >> 5)) * 64 +
            (size_t)((m & 15) | (((k >> 3) & 3) << 4))) * 8 + (k & 7);
}

// ---------------------------------------------------------------------------
// K1: fused setup. blocks 0..255: partial column stats (seq axis).
// blocks 256..2303: weight cast into frag-major layouts (wqkv_f K=1024,
// wo_f K=512) via 32x32 LDS tiles.
__global__ __launch_bounds__(256) void setup_fused(
    const float* __restrict__ x, float* __restrict__ ps, float* __restrict__ pq,
    const float* __restrict__ wq, const float* __restrict__ wkv,
    const float* __restrict__ wo, ushort* __restrict__ wqkv_f,
    ushort* __restrict__ wo_f) {
    __shared__ float tile[32][33];
    int bid = blockIdx.x;
    if (bid < 256) {
        int gd = (bid & 7) * 256 + threadIdx.x;   // b*1024 + c
        int ch = bid >> 3;                        // 0..31
        int b = gd >> 10;
        const float* p = x + (size_t)(b * N_ + ch * 64) * DIM_ + (gd & 1023);
        float s = 0.f, q = 0.f;
#pragma unroll 4
        for (int n = 0; n < 64; ++n) { float v = p[(size_t)n * DIM_]; s += v; q += v * v; }
        ps[ch * 2048 + gd] = s;
        pq[ch * 2048 + gd] = q;
        return;
    }
    int t = bid - 256;
    const float* src; ushort* dst; int C, K, k0, ncol0, nglob0; float scale;
    if (t < 512) {          // wq: (1024 k x 512 n), 32x16 tiles
        int kt = t >> 4, nt = t & 15;
        src = wq; dst = wqkv_f; C = 512; K = 1024; scale = QSCALE;
        k0 = kt * 32; ncol0 = nt * 32; nglob0 = ncol0;
    } else if (t < 1536) {  // wkv: (1024 k x 1024 n) -> n-global 512..1535
        int u = t - 512; int kt = u >> 5, nt = u & 31;
        src = wkv; dst = wqkv_f; C = 1024; K = 1024; scale = 1.f;
        k0 = kt * 32; ncol0 = nt * 32; nglob0 = 512 + ncol0;
    } else {                // wo: (512 k x 1024 n)
        int u = t - 1536; int kt = u >> 5, nt = u & 31;
        src = wo; dst = wo_f; C = 1024; K = 512; scale = 1.f;
        k0 = kt * 32; ncol0 = nt * 32; nglob0 = ncol0;
    }
    int ti = threadIdx.x >> 5, tj = threadIdx.x & 31;
#pragma unroll
    for (int p = 0; p < 4; ++p)
        tile[ti + 8 * p][tj] = src[(size_t)(k0 + ti + 8 * p) * C + ncol0 + tj] * scale;
    __syncthreads();
    if (threadIdx.x < 128) {
        int nl = threadIdx.x & 31, kc8 = threadIdx.x >> 5;   // 0..3
        union { ushort us[8]; uint4 v; } u;
#pragma unroll
        for (int ii = 0; ii < 8; ++ii) u.us[ii] = f2bf(tile[kc8 * 8 + ii][nl]);
        *(uint4*)&dst[frag_off(nglob0 + nl, k0 + kc8 * 8, K >> 5)] = u.v;
    }
}

// ---------------------------------------------------------------------------
// K2: fused finalize + normalize + cast to frag-major xn. grid 512, block 256.
// block = (b, c-slab of 64, n-chunk of 128); finalize recomputed per chunk.
__global__ __launch_bounds__(256) void finalize_norm(
    const float* __restrict__ ps, const float* __restrict__ pq,
    const float* __restrict__ x, const float* __restrict__ g,
    ushort* __restrict__ xnf) {
    __shared__ float s4[4][64], q4[4][64], aa[64], bb[64];
    int t = threadIdx.x;
    int b = blockIdx.x >> 8, slab = (blockIdx.x >> 4) & 15, nch = blockIdx.x & 15;
    int c0 = slab * 64;
    {
        int c = t & 63, grp = t >> 6;
        float s = 0.f, q = 0.f;
#pragma unroll
        for (int ch = 0; ch < 8; ++ch) {
            int o = (grp * 8 + ch) * 2048 + b * 1024 + c0 + c;
            s += ps[o]; q += pq[o];
        }
        s4[grp][c] = s; q4[grp][c] = q;
    }
    __syncthreads();
    if (t < 64) {
        float s = s4[0][t] + s4[1][t] + s4[2][t] + s4[3][t];
        float q = q4[0][t] + q4[1][t] + q4[2][t] + q4[3][t];
        float mean = s * (1.f / N_);
        float var = q * (1.f / N_) - mean * mean;
        float rstd = rsqrtf(var + 1e-5f);
        float a = rstd * g[c0 + t];
        aa[t] = a; bb[t] = -mean * a;
    }
    __syncthreads();
    int c4 = (t & 15) * 4, ro = t >> 4;
#pragma unroll
    for (int it = 0; it < 8; ++it) {
        int r = nch * 128 + it * 16 + ro;          // row within b
        int m = b * 2048 + r;
        float4 xv = *(const float4*)&x[(size_t)m * DIM_ + c0 + c4];
        float v0 = xv.x * aa[c4 + 0] + bb[c4 + 0];
        float v1 = xv.y * aa[c4 + 1] + bb[c4 + 1];
        float v2 = xv.z * aa[c4 + 2] + bb[c4 + 2];
        float v3 = xv.w * aa[c4 + 3] + bb[c4 + 3];
        uint2 u; u.x = pkbf(v0, v1); u.y = pkbf(v2, v3);
        *(uint2*)&xnf[frag_off(m, c0 + c4, 32)] = u;
    }
}

// ---------------------------------------------------------------------------
// LDS-free GEMM core: wave tile 64x64 as 4x4 MFMA 16x16x32, both operands
// frag-major in global (L2/L3-hot), 2-stage register pipeline, no barriers.
template <int NKC>
__device__ __forceinline__ void gemm_core(
    const ushort* __restrict__ pA, const ushort* __restrict__ pB,
    floatx4 (&acc)[4][4]) {
    constexpr int TS = NKC * 512;     // m-tile stride (elems)
    bf16x8 a0[4], b0[4], a1[4], b1[4];
#pragma unroll
    for (int i = 0; i < 4; ++i) {
        a0[i] = *(const bf16x8*)(pA + (size_t)i * TS);
        b0[i] = *(const bf16x8*)(pB + (size_t)i * TS);
    }
    for (int kc = 0; kc < NKC; kc += 2) {
#pragma unroll
        for (int i = 0; i < 4; ++i) {
            a1[i] = *(const bf16x8*)(pA + (size_t)i * TS + (size_t)(kc + 1) * 512);
            b1[i] = *(const bf16x8*)(pB + (size_t)i * TS + (size_t)(kc + 1) * 512);
        }
#pragma unroll
        for (int mi = 0; mi < 4; ++mi)
#pragma unroll
            for (int ni = 0; ni < 4; ++ni)
                acc[mi][ni] = __builtin_amdgcn_mfma_f32_16x16x32_bf16(
                    a0[mi], b0[ni], acc[mi][ni], 0, 0, 0);
        if (kc + 2 < NKC) {
#pragma unroll
            for (int i = 0; i < 4; ++i) {
                a0[i] = *(const bf16x8*)(pA + (size_t)i * TS + (size_t)(kc + 2) * 512);
                b0[i] = *(const bf16x8*)(pB + (size_t)i * TS + (size_t)(kc + 2) * 512);
            }
        }
#pragma unroll
        for (int mi = 0; mi < 4; ++mi)
#pragma unroll
            for (int ni = 0; ni < 4; ++ni)
                acc[mi][ni] = __builtin_amdgcn_mfma_f32_16x16x32_bf16(
                    a1[mi], b1[ni], acc[mi][ni], 0, 0, 0);
    }
}

// K3: qkv GEMM. grid (64, 12), block 128 (2 waves side-by-side in N).
// by<8: Q|K -> qk row-major [4096][1024] (q pre-scaled via wq).
// by>=8: V -> vT[bh][d][n] transposed, packed b64 stores (vtrans fused).
__global__ __launch_bounds__(128) void gemm_qkv(
    const ushort* __restrict__ xnf, const ushort* __restrict__ wf,
    ushort* __restrict__ qk, ushort* __restrict__ vT) {
    int tx = threadIdx.x, w = tx >> 6, l = tx & 63;
    int lr = l & 15, lq = l >> 4;
    int bx = blockIdx.x, by = blockIdx.y;
    const ushort* pA = xnf + (size_t)(bx * 4) * 32 * 512 + l * 8;
    const ushort* pB = wf + (size_t)(by * 8 + w * 4) * 32 * 512 + l * 8;
    floatx4 acc[4][4] = {};
    gemm_core<32>(pA, pB, acc);
    int col0 = by * 128 + w * 64;
    if (by < 8) {
#pragma unroll
        for (int mi = 0; mi < 4; ++mi)
#pragma unroll
            for (int ni = 0; ni < 4; ++ni) {
                int col = col0 + 16 * ni + lr;
#pragma unroll
                for (int reg = 0; reg < 4; ++reg) {
                    int row = bx * 64 + 16 * mi + 4 * lq + reg;
                    qk[(size_t)row * 1024 + col] = f2bf(acc[mi][ni][reg]);
                }
            }
    } else {
#pragma unroll
        for (int mi = 0; mi < 4; ++mi) {
            int row0 = bx * 64 + 16 * mi + 4 * lq;
            int bb2 = row0 >> 11, nn = row0 & 2047;
#pragma unroll
            for (int ni = 0; ni < 4; ++ni) {
                int cv = col0 - 1024 + 16 * ni + lr;
                int h = cv >> 6, d = cv & 63;
                uint2 u;
                u.x = pkbf(acc[mi][ni][0], acc[mi][ni][1]);
                u.y = pkbf(acc[mi][ni][2], acc[mi][ni][3]);
                *(uint2*)&vT[((size_t)((bb2 * 8 + h) * 64 + d)) * 2048 + nn] = u;
            }
        }
    }
}

// K6: out GEMM. grid (64, 8), block 128. A = attn frag-major (K=512),
// B = wo frag-major, out fp32 row-major.
__global__ __launch_bounds__(128) void gemm_out(
    const ushort* __restrict__ af, const ushort* __restrict__ wf,
    float* __restrict__ out) {
    int tx = threadIdx.x, w = tx >> 6, l = tx & 63;
    int lr = l & 15, lq = l >> 4;
    int bx = blockIdx.x, by = blockIdx.y;
    const ushort* pA = af + (size_t)(bx * 4) * 16 * 512 + l * 8;
    const ushort* pB = wf + (size_t)(by * 8 + w * 4) * 16 * 512 + l * 8;
    floatx4 acc[4][4] = {};
    gemm_core<16>(pA, pB, acc);
    int col0 = by * 128 + w * 64;
#pragma unroll
    for (int mi = 0; mi < 4; ++mi)
#pragma unroll
        for (int ni = 0; ni < 4; ++ni) {
            int col = col0 + 16 * ni + lr;
#pragma unroll
            for (int reg = 0; reg < 4; ++reg) {
                int row = bx * 64 + 16 * mi + 4 * lq + reg;
                out[(size_t)row * 1024 + col] = acc[mi][ni][reg];
            }
        }
}

// ---------------------------------------------------------------------------
// K4: split-KV flash (as round 3; qk stride now 1024, V from vT).
__global__ __launch_bounds__(256, 4) void flash_attn(
    const ushort* __restrict__ qk, const ushort* __restrict__ vT,
    float* __restrict__ po, float* __restrict__ pl, int nkt) {
    __shared__ __align__(16) ushort sK[64 * 64];
    __shared__ __align__(16) ushort sV[64 * 64];
    __shared__ __align__(16) ushort sPQ[4 * 32 * 72];

    const int tx = threadIdx.x;
    const int w = tx >> 6, l = tx & 63;
    const int lr = l & 15, lq = l >> 4;
    const int qt = blockIdx.x, bh = blockIdx.y, sp = blockIdx.z;
    const int b = bh >> 3, h = bh & 7;
    const size_t rowbase = (size_t)b * N_;
    const int qbase = qt * 128;
    const int kbase = sp * nkt * 64;

    const int rl = l >> 3;
    const int swz8 = ((l & 7) ^ rl) * 8;
    const int fr0 = (lq ^ (lr & 7)) * 8;
    const int fr1 = ((4 + lq) ^ (lr & 7)) * 8;

#pragma unroll
    for (int i = 0; i < 4; ++i) {
        int r0 = 32 * w + 8 * i;
        gld_lds(qk + (rowbase + qbase + r0 + rl) * 1024 + h * DH_ + swz8,
                &sPQ[r0 * 64]);
    }
    __syncthreads();
    bf16x8 bq[2][2];
#pragma unroll
    for (int qq = 0; qq < 2; ++qq) {
        int r = (32 * w + 16 * qq + lr) * 64;
        bq[qq][0] = *(const bf16x8*)&sPQ[r + fr0];
        bq[qq][1] = *(const bf16x8*)&sPQ[r + fr1];
    }

    floatx4 o[2][4] = {};
    float lsum[2] = {0.f, 0.f};

    for (int kt = 0; kt < nkt; ++kt) {
        __syncthreads();
#pragma unroll
        for (int i = 0; i < 2; ++i) {
            int r0 = 16 * w + 8 * i;
            gld_lds(qk + (rowbase + kbase + kt * 64 + r0 + rl) * 1024 + 512 + h * DH_ + swz8,
                    &sK[r0 * 64]);
            gld_lds(vT + ((size_t)bh * DH_ + r0 + rl) * N_ + kbase + kt * 64 + swz8,
                    &sV[r0 * 64]);
        }
        __syncthreads();

        floatx4 c[4][2] = {};
#pragma unroll
        for (int s = 0; s < 2; ++s) {
            const int fo = s ? fr1 : fr0;
            bf16x8 ak[4];
#pragma unroll
            for (int kk = 0; kk < 4; ++kk)
                ak[kk] = *(const bf16x8*)&sK[(16 * kk + lr) * 64 + fo];
#pragma unroll
            for (int kk = 0; kk < 4; ++kk)
#pragma unroll
                for (int qq = 0; qq < 2; ++qq)
                    c[kk][qq] = __builtin_amdgcn_mfma_f32_16x16x32_bf16(
                        ak[kk], bq[qq][s], c[kk][qq], 0, 0, 0);
        }

#pragma unroll
        for (int kk = 0; kk < 4; ++kk)
#pragma unroll
            for (int qq = 0; qq < 2; ++qq) {
                float e0 = EXP2(c[kk][qq][0]);
                float e1 = EXP2(c[kk][qq][1]);
                float e2 = EXP2(c[kk][qq][2]);
                float e3 = EXP2(c[kk][qq][3]);
                lsum[qq] += (e0 + e1) + (e2 + e3);
                uint2 u; u.x = pkbf(e0, e1); u.y = pkbf(e2, e3);
                *(uint2*)&sPQ[(32 * w + 16 * qq + lr) * 72 + 16 * kk + 4 * lq] = u;
            }

#pragma unroll
        for (int s = 0; s < 2; ++s) {
            const int fo = s ? fr1 : fr0;
            bf16x8 ap[2], bv[4];
#pragma unroll
            for (int mi = 0; mi < 2; ++mi)
                ap[mi] = *(const bf16x8*)&sPQ[(32 * w + 16 * mi + lr) * 72 + 32 * s + 8 * lq];
#pragma unroll
            for (int dt = 0; dt < 4; ++dt)
                bv[dt] = *(const bf16x8*)&sV[(16 * dt + lr) * 64 + fo];
#pragma unroll
            for (int mi = 0; mi < 2; ++mi)
#pragma unroll
                for (int dt = 0; dt < 4; ++dt)
                    o[mi][dt] = __builtin_amdgcn_mfma_f32_16x16x32_bf16(
                        ap[mi], bv[dt], o[mi][dt], 0, 0, 0);
        }
    }

#pragma unroll
    for (int qq = 0; qq < 2; ++qq) {
        lsum[qq] += __shfl_xor(lsum[qq], 16);
        lsum[qq] += __shfl_xor(lsum[qq], 32);
    }
    float* pob = po + (size_t)sp * POSTRIDE;
    if (lq == 0) {
#pragma unroll
        for (int qq = 0; qq < 2; ++qq)
            pl[((size_t)sp * 16 + bh) * N_ + qbase + 32 * w + 16 * qq + lr] = lsum[qq];
    }
    const size_t obase = (size_t)bh * N_;
#pragma unroll
    for (int mi = 0; mi < 2; ++mi)
#pragma unroll
        for (int dt = 0; dt < 4; ++dt)
#pragma unroll
            for (int reg = 0; reg < 4; ++reg) {
                int row = qbase + 32 * w + 16 * mi + 4 * lq + reg;
                pob[(obase + row) * DH_ + 16 * dt + lr] = o[mi][dt][reg];
            }
}

// K5: merge splits + normalize + cast; writes attn in frag-major (K=512).
__global__ __launch_bounds__(256) void merge_attn(
    const float* __restrict__ po, const float* __restrict__ pl,
    ushort* __restrict__ attnf, int nsplit) {
    int idx = blockIdx.x * 256 + threadIdx.x;
    int d4 = (idx & 15) * 4;
    int h = (idx >> 4) & 7;
    int rowg = idx >> 7;
    int b = rowg >> 11, r = rowg & 2047;
    size_t pbase = ((size_t)b * 8 + h) * N_ + r;
    float4 acc = *(const float4*)&po[pbase * DH_ + d4];
    float lv = pl[pbase];
    for (int s = 1; s < nsplit; ++s) {
        float4 a1 = *(const float4*)&po[(size_t)s * POSTRIDE + pbase * DH_ + d4];
        acc.x += a1.x; acc.y += a1.y; acc.z += a1.z; acc.w += a1.w;
        lv += pl[((size_t)s * 16) * N_ + pbase];
    }
    float inv = 1.f / lv;
    uint2 u;
    u.x = pkbf(acc.x * inv, acc.y * inv);
    u.y = pkbf(acc.z * inv, acc.w * inv);
    *(uint2*)&attnf[frag_off(rowg, h * DH_ + d4, 16)] = u;
}

// ---------------------------------------------------------------------------
extern "C" void kernel_launch(void* const* d_in, const int* in_sizes, int n_in,
                              void* d_out, int out_size, void* d_ws, size_t ws_size,
                              hipStream_t stream) {
    const float* x   = (const float*)d_in[0];
    const float* g   = (const float*)d_in[1];
    const float* wq  = (const float*)d_in[2];
    const float* wkv = (const float*)d_in[3];
    const float* wo  = (const float*)d_in[4];
    float* out = (float*)d_out;

    char* ws = (char*)d_ws;
    float*  psum   = (float*)(ws + 0);          // 256K
    float*  psqr   = (float*)(ws + 262144);     // 256K
    ushort* xnf    = (ushort*)(ws + 524288);    // 8.39M frag-major K=1024
    ushort* wqkv_f = (ushort*)(ws + 8912896);   // 3.15M frag-major K=1024
    ushort* wo_f   = (ushort*)(ws + 12058624);  // 1.05M frag-major K=512
    ushort* qkb    = (ushort*)(ws + 13107200);  // 8.39M row-major [4096][1024]
    ushort* vTb    = (ushort*)(ws + 21495808);  // 4.19M [bh][d][n]
    ushort* attnf  = (ushort*)(ws + 25690112);  // 4.19M frag-major K=512
    float*  plb    = (float*)(ws + 29884416);   // 512K
    float*  pob    = (float*)(ws + 30408704);   // 4 x 8.39M -> end ~64M

    const int nsplit = (ws_size >= (size_t)66 * 1024 * 1024) ? 4
                     : (ws_size >= (size_t)48 * 1024 * 1024) ? 2 : 1;

    setup_fused<<<2304, 256, 0, stream>>>(x, psum, psqr, wq, wkv, wo, wqkv_f, wo_f);
    finalize_norm<<<512, 256, 0, stream>>>(psum, psqr, x, g, xnf);
    gemm_qkv<<<dim3(64, 12), 128, 0, stream>>>(xnf, wqkv_f, qkb, vTb);
    flash_attn<<<dim3(16, 16, nsplit), 256, 0, stream>>>(qkb, vTb, pob, plb, 32 / nsplit);
    merge_attn<<<2048, 256, 0, stream>>>(pob, plb, attnf, nsplit);
    gemm_out<<<dim3(64, 8), 128, 0, stream>>>(attnf, wo_f, out);
}